// Round 2
// baseline (144.209 us; speedup 1.0000x reference)
//
#include <hip/hip_runtime.h>
#include <hip/hip_cooperative_groups.h>
#include <math.h>

namespace cg = cooperative_groups;

// Sizes (compile-time constants from the reference)
#define N_A 64
#define N_B 128
#define N_C 128
#define D_IN 256
#define D_H 32
#define NHEADS 4
#define DMODEL (D_H * NHEADS)   // 128

// Workspace layout (float offsets)
#define OFF_Q    0
#define OFF_KB   (OFF_Q   + N_A*DMODEL)
#define OFF_KC   (OFF_KB  + N_B*DMODEL)
#define OFF_VB   (OFF_KC  + N_C*DMODEL)
#define OFF_VC   (OFF_VB  + N_B*DMODEL)
#define OFF_SAB  (OFF_VC  + N_C*DMODEL)
#define OFF_SAC  (OFF_SAB + N_A*NHEADS*N_B)
#define OFF_SBC  (OFF_SAC + N_A*NHEADS*N_C)
#define OFF_PB   (OFF_SBC + NHEADS*N_B*N_C)
#define OFF_PC   (OFF_PB  + N_B*NHEADS*4)
#define OFF_M    (OFF_PC  + N_C*NHEADS*4)
#define OFF_Z    (OFF_M   + N_A*NHEADS)

#define SCALE 0.17677669529663687f  // 1/sqrt(32)

__global__ __launch_bounds__(256) void fused_kernel(
    const float* __restrict__ Ha, const float* __restrict__ Hb,
    const float* __restrict__ Hc, const float* __restrict__ Wq,
    const float* __restrict__ Wk, const float* __restrict__ Wv,
    const float* __restrict__ fcw, const float* __restrict__ fcb,
    float* __restrict__ out, float* __restrict__ ws)
{
  cg::grid_group grid = cg::this_grid();
  const int t   = threadIdx.x;   // 0..255
  const int bid = blockIdx.x;    // 0..255

  // ---------------- Phase 1: projections Q, Kb, Kc, Vb, Vc ----------------
  // 576 rows -> 288 pairs; block handles one pair per iteration (2 rows x 128 cols).
  {
    __shared__ float xs[2][D_IN];
    const int half = t >> 7;     // which row of the pair
    const int col  = t & 127;
    for (int pair = bid; pair < 288; pair += 256) {
      int row = pair * 2 + half;
      const float* X; const float* W; float* Y; int r;
      if (row < 64)       { X = Ha; W = Wq; Y = ws + OFF_Q;  r = row; }
      else if (row < 192) { X = Hb; W = Wk; Y = ws + OFF_KB; r = row - 64; }
      else if (row < 320) { X = Hc; W = Wk; Y = ws + OFF_KC; r = row - 192; }
      else if (row < 448) { X = Hb; W = Wv; Y = ws + OFF_VB; r = row - 320; }
      else                { X = Hc; W = Wv; Y = ws + OFF_VC; r = row - 448; }
      xs[half][col]       = X[r * D_IN + col];
      xs[half][col + 128] = X[r * D_IN + col + 128];
      __syncthreads();
      float acc = 0.0f;
      #pragma unroll 8
      for (int i = 0; i < D_IN; ++i)
        acc = fmaf(xs[half][i], W[i * DMODEL + col], acc);
      Y[r * DMODEL + col] = acc;
      __syncthreads();
    }
  }
  grid.sync();

  // ---------------- Phase 2: s_ab, s_ac, s_bc (pre-scaled), pb, pc ----------
  {
    const float* Q  = ws + OFF_Q;
    const float* Kb = ws + OFF_KB;
    const float* Kc = ws + OFF_KC;
    const float* Vb = ws + OFF_VB;
    const float* Vc = ws + OFF_VC;
    for (int idx = bid * 256 + t; idx < 135168; idx += 65536) {
      if (idx < 32768) {
        int b = idx & 127; int ah = idx >> 7; int a = ah >> 2; int h = ah & 3;
        const float* q = Q  + a * DMODEL + h * D_H;
        const float* k = Kb + b * DMODEL + h * D_H;
        float acc = 0.0f;
        #pragma unroll
        for (int d = 0; d < D_H; ++d) acc = fmaf(q[d], k[d], acc);
        ws[OFF_SAB + idx] = acc * SCALE;
      } else if (idx < 65536) {
        int j = idx - 32768;
        int c = j & 127; int ah = j >> 7; int a = ah >> 2; int h = ah & 3;
        const float* q = Q  + a * DMODEL + h * D_H;
        const float* k = Kc + c * DMODEL + h * D_H;
        float acc = 0.0f;
        #pragma unroll
        for (int d = 0; d < D_H; ++d) acc = fmaf(q[d], k[d], acc);
        ws[OFF_SAC + j] = acc * SCALE;
      } else if (idx < 131072) {
        int j = idx - 65536;               // (h*128+b)*128 + c
        int c = j & 127; int hb = j >> 7; int h = hb >> 7; int b = hb & 127;
        const float* kb = Kb + b * DMODEL + h * D_H;
        const float* kc = Kc + c * DMODEL + h * D_H;
        float acc = 0.0f;
        #pragma unroll
        for (int d = 0; d < D_H; ++d) acc = fmaf(kb[d], kc[d], acc);
        ws[OFF_SBC + j] = acc * SCALE;
      } else if (idx < 133120) {
        int j = idx - 131072;              // pb[(b*4+h)*4+kk]
        int kk = j & 3; int h = (j >> 2) & 3; int b = j >> 4;
        const float* v = Vb + b * DMODEL + h * D_H;
        const float* w = fcw + kk * D_H;
        float acc = 0.0f;
        #pragma unroll
        for (int d = 0; d < D_H; ++d) acc = fmaf(v[d], w[d], acc);
        ws[OFF_PB + j] = acc;
      } else if (idx < 135168) {
        int j = idx - 133120;              // pc[(c*4+h)*4+kk]
        int kk = j & 3; int h = (j >> 2) & 3; int c = j >> 4;
        const float* v = Vc + c * DMODEL + h * D_H;
        const float* w = fcw + kk * D_H;
        float acc = 0.0f;
        #pragma unroll
        for (int d = 0; d < D_H; ++d) acc = fmaf(v[d], w[d], acc);
        ws[OFF_PC + j] = acc;
      }
    }
  }
  grid.sync();

  // ---------------- Phase 3: softmax stats m, Z per (a,h) = block bid -------
  {
    const int ah = bid;                    // 0..255, grid is exactly 256 blocks
    const int h = ah & 3;
    const float* pab = ws + OFF_SAB + ah * N_B;
    const float* pac = ws + OFF_SAC + ah * N_C;
    const float* pbc = ws + OFF_SBC + h * N_B * N_C;

    float mx = -1e30f;
    for (int i = t; i < N_B * N_C; i += 256) {
      int b = i >> 7; int c = i & 127;
      float s = pab[b] + pac[c] + pbc[i];
      mx = fmaxf(mx, s);
    }
    __shared__ float redm[4];
    #pragma unroll
    for (int o = 32; o > 0; o >>= 1) mx = fmaxf(mx, __shfl_down(mx, o, 64));
    if ((t & 63) == 0) redm[t >> 6] = mx;
    __syncthreads();
    float mall = fmaxf(fmaxf(redm[0], redm[1]), fmaxf(redm[2], redm[3]));

    float sum = 0.0f;
    for (int i = t; i < N_B * N_C; i += 256) {
      int b = i >> 7; int c = i & 127;
      float s = pab[b] + pac[c] + pbc[i];
      sum += __expf(s - mall);
    }
    __shared__ float redz[4];
    #pragma unroll
    for (int o = 32; o > 0; o >>= 1) sum += __shfl_down(sum, o, 64);
    if ((t & 63) == 0) redz[t >> 6] = sum;
    __syncthreads();
    if (t == 0) {
      ws[OFF_M + ah] = mall;
      ws[OFF_Z + ah] = redz[0] + redz[1] + redz[2] + redz[3];
    }
  }
  grid.sync();

  // ---------------- Phase 4: fused output -----------------
  // out[a,b,c] = sigmoid( sum_kk alpha*(pb+pc) + fc_b ),
  // h = b>>5, bb = ((b&31)<<2)|(c>>5), cc = ((c&31)<<2)|kk.
  {
    const float fb = fcb[0];
    for (int idx = bid * 256 + t; idx < N_A * N_B * N_C; idx += 65536) {
      int a = idx >> 14;
      int rem = idx & 16383;
      int b = rem >> 7;
      int c = rem & 127;

      int h  = b >> 5;
      int bb = ((b & 31) << 2) | (c >> 5);
      int ah = a * 4 + h;

      float sabv = ws[OFF_SAB + ah * N_B + bb];
      float mv   = ws[OFF_M + ah];
      float zinv = 1.0f / ws[OFF_Z + ah];
      const float* pacRow = ws + OFF_SAC + ah * N_C;
      const float* pbcRow = ws + OFF_SBC + (h * N_B + bb) * N_C;
      const float* pbRow  = ws + OFF_PB + (bb * 4 + h) * 4;

      float acc = 0.0f;
      #pragma unroll
      for (int kk = 0; kk < 4; ++kk) {
        int cc = ((c & 31) << 2) | kk;
        float s = sabv + pacRow[cc] + pbcRow[cc];
        float alpha = __expf(s - mv) * zinv;
        float pv = pbRow[kk] + ws[OFF_PC + (cc * 4 + h) * 4 + kk];
        acc = fmaf(alpha, pv, acc);
      }
      float x = acc + fb;
      out[idx] = 1.0f / (1.0f + __expf(-x));
    }
  }
}

extern "C" void kernel_launch(void* const* d_in, const int* in_sizes, int n_in,
                              void* d_out, int out_size, void* d_ws, size_t ws_size,
                              hipStream_t stream) {
  const float* Ha  = (const float*)d_in[0];
  const float* Hb  = (const float*)d_in[1];
  const float* Hc  = (const float*)d_in[2];
  const float* Wq  = (const float*)d_in[3];
  const float* Wk  = (const float*)d_in[4];
  const float* Wv  = (const float*)d_in[5];
  const float* fcw = (const float*)d_in[6];
  const float* fcb = (const float*)d_in[7];
  float* out = (float*)d_out;
  float* ws  = (float*)d_ws;

  void* args[] = { &Ha, &Hb, &Hc, &Wq, &Wk, &Wv, &fcw, &fcb, &out, &ws };
  hipLaunchCooperativeKernel((const void*)fused_kernel,
                             dim3(256), dim3(256), args, 0, stream);
}

// Round 5
// 28.248 us; speedup vs baseline: 5.1052x; 5.1052x over previous
//
#include <hip/hip_runtime.h>
#include <math.h>

#define N_A 64
#define N_B 128
#define N_C 128
#define D_IN 256
#define D_H 32
#define NHEADS 4
#define DMODEL (D_H * NHEADS)   // 128

// Workspace layout (float offsets)
#define OFF_Q    0
#define OFF_KB   (OFF_Q   + N_A*DMODEL)
#define OFF_KC   (OFF_KB  + N_B*DMODEL)
#define OFF_VB   (OFF_KC  + N_C*DMODEL)
#define OFF_VC   (OFF_VB  + N_B*DMODEL)
#define OFF_EAB  (OFF_VC  + N_C*DMODEL)      // exp(sab) [ah][b]
#define OFF_EAC  (OFF_EAB + N_A*NHEADS*N_B)  // exp(sac) [ah][c]
#define OFF_EBC  (OFF_EAC + N_A*NHEADS*N_C)  // exp(sbc) [h][b][c]
#define OFF_PB   (OFF_EBC + NHEADS*N_B*N_C)  // [b][h][kk]
#define OFF_PC   (OFF_PB  + N_B*NHEADS*4)    // [c][h][kk]
#define OFF_ZI   (OFF_PC  + N_C*NHEADS*4)    // 1/Z per [ah]

#define SCALE 0.17677669529663687f  // 1/sqrt(32)

// ---------------- K1: projections (288 blocks x 256 thr, 2 rows/block) ----
__global__ __launch_bounds__(256) void proj_kernel(
    const float* __restrict__ Ha, const float* __restrict__ Hb,
    const float* __restrict__ Hc, const float* __restrict__ Wq,
    const float* __restrict__ Wk, const float* __restrict__ Wv,
    float* __restrict__ ws) {
  __shared__ float xs[2][D_IN];
  const int t = threadIdx.x;
  const int half = t >> 7;      // which row of the pair
  const int col  = t & 127;
  const int row  = blockIdx.x * 2 + half;

  const float* X; const float* W; float* Y; int r;
  if (row < 64)       { X = Ha; W = Wq; Y = ws + OFF_Q;  r = row; }
  else if (row < 192) { X = Hb; W = Wk; Y = ws + OFF_KB; r = row - 64; }
  else if (row < 320) { X = Hc; W = Wk; Y = ws + OFF_KC; r = row - 192; }
  else if (row < 448) { X = Hb; W = Wv; Y = ws + OFF_VB; r = row - 320; }
  else                { X = Hc; W = Wv; Y = ws + OFF_VC; r = row - 448; }

  xs[half][col]       = X[r * D_IN + col];
  xs[half][col + 128] = X[r * D_IN + col + 128];
  __syncthreads();
  float acc = 0.0f;
  #pragma unroll 8
  for (int i = 0; i < D_IN; ++i)
    acc = fmaf(xs[half][i], W[i * DMODEL + col], acc);
  Y[r * DMODEL + col] = acc;
}

// ---------------- K2: E-scores (exp, no max shift) + pb/pc ----------------
__global__ __launch_bounds__(256) void scores_kernel(
    const float* __restrict__ fcw, float* __restrict__ ws) {
  const int idx = blockIdx.x * 256 + threadIdx.x;   // < 135168
  if (idx < 32768) {
    int b = idx & 127; int ah = idx >> 7; int a = ah >> 2; int h = ah & 3;
    const float4* q = (const float4*)(ws + OFF_Q  + a * DMODEL + h * D_H);
    const float4* k = (const float4*)(ws + OFF_KB + b * DMODEL + h * D_H);
    float acc = 0.0f;
    #pragma unroll
    for (int d = 0; d < 8; ++d) {
      float4 qv = q[d], kv = k[d];
      acc = fmaf(qv.x, kv.x, fmaf(qv.y, kv.y, fmaf(qv.z, kv.z, fmaf(qv.w, kv.w, acc))));
    }
    ws[OFF_EAB + idx] = __expf(acc * SCALE);
  } else if (idx < 65536) {
    int j = idx - 32768;
    int c = j & 127; int ah = j >> 7; int a = ah >> 2; int h = ah & 3;
    const float4* q = (const float4*)(ws + OFF_Q  + a * DMODEL + h * D_H);
    const float4* k = (const float4*)(ws + OFF_KC + c * DMODEL + h * D_H);
    float acc = 0.0f;
    #pragma unroll
    for (int d = 0; d < 8; ++d) {
      float4 qv = q[d], kv = k[d];
      acc = fmaf(qv.x, kv.x, fmaf(qv.y, kv.y, fmaf(qv.z, kv.z, fmaf(qv.w, kv.w, acc))));
    }
    ws[OFF_EAC + j] = __expf(acc * SCALE);
  } else if (idx < 131072) {
    int j = idx - 65536;               // (h*128+b)*128 + c
    int c = j & 127; int hb = j >> 7; int h = hb >> 7; int b = hb & 127;
    const float4* kb = (const float4*)(ws + OFF_KB + b * DMODEL + h * D_H);
    const float4* kc = (const float4*)(ws + OFF_KC + c * DMODEL + h * D_H);
    float acc = 0.0f;
    #pragma unroll
    for (int d = 0; d < 8; ++d) {
      float4 xv = kb[d], yv = kc[d];
      acc = fmaf(xv.x, yv.x, fmaf(xv.y, yv.y, fmaf(xv.z, yv.z, fmaf(xv.w, yv.w, acc))));
    }
    ws[OFF_EBC + j] = __expf(acc * SCALE);
  } else if (idx < 133120) {
    int j = idx - 131072;              // pb[(b*4+h)*4+kk]
    int kk = j & 3; int h = (j >> 2) & 3; int b = j >> 4;
    const float* v = ws + OFF_VB + b * DMODEL + h * D_H;
    const float* w = fcw + kk * D_H;
    float acc = 0.0f;
    #pragma unroll
    for (int d = 0; d < D_H; ++d) acc = fmaf(v[d], w[d], acc);
    ws[OFF_PB + j] = acc;
  } else if (idx < 135168) {
    int j = idx - 133120;              // pc[(c*4+h)*4+kk]
    int kk = j & 3; int h = (j >> 2) & 3; int c = j >> 4;
    const float* v = ws + OFF_VC + c * DMODEL + h * D_H;
    const float* w = fcw + kk * D_H;
    float acc = 0.0f;
    #pragma unroll
    for (int d = 0; d < D_H; ++d) acc = fmaf(v[d], w[d], acc);
    ws[OFF_PC + j] = acc;
  }
}

// ---------------- K3: ZI[ah] via factorized bilinear form ------------------
// Z = sum_b Eab[b] * (sum_c Ebc[h,b,c] * Eac[c]); block = ah, c split by 2.
__global__ __launch_bounds__(256) void z_kernel(float* __restrict__ ws) {
  __shared__ float red[4];
  const int ah = blockIdx.x, h = ah & 3;
  const int t = threadIdx.x;
  const int b = t & 127, half = t >> 7;
  const float4* eac = (const float4*)(ws + OFF_EAC + ah * N_C + half * 64);
  const float4* ebc = (const float4*)(ws + OFF_EBC + (h * N_B + b) * N_C + half * 64);
  float u = 0.0f;
  #pragma unroll 4
  for (int i = 0; i < 16; ++i) {
    float4 ev = ebc[i], av = eac[i];
    u = fmaf(ev.x, av.x, fmaf(ev.y, av.y, fmaf(ev.z, av.z, fmaf(ev.w, av.w, u))));
  }
  float v = ws[OFF_EAB + ah * N_B + b] * u;
  #pragma unroll
  for (int o = 32; o > 0; o >>= 1) v += __shfl_down(v, o, 64);
  if ((t & 63) == 0) red[t >> 6] = v;
  __syncthreads();
  if (t == 0) ws[OFF_ZI + ah] = 1.0f / (red[0] + red[1] + red[2] + red[3]);
}

// ---------------- K4: output ----------------------------------------------
// idx enumerates (a in [0,32), b, c); each thread also does a+32 (shared loads).
// h = b>>5, bb = ((b&31)<<2)|(c>>5), cc = base|kk, base = (c&31)<<2.
__global__ __launch_bounds__(256) void out_kernel(
    const float* __restrict__ ws, const float* __restrict__ fcb,
    float* __restrict__ out) {
  const float fb = fcb[0];
  const int idx = blockIdx.x * 256 + threadIdx.x;    // < 524288
  const int a   = idx >> 14;
  const int rem = idx & 16383;
  const int b   = rem >> 7;
  const int c   = rem & 127;

  const int h    = b >> 5;
  const int bb   = ((b & 31) << 2) | (c >> 5);
  const int base = (c & 31) << 2;

  const float4 ebc4 = *(const float4*)(ws + OFF_EBC + (h * N_B + bb) * N_C + base);
  const float4 pb4  = *(const float4*)(ws + OFF_PB + bb * 16 + h * 4);
  const float pv0 = pb4.x + ws[OFF_PC + (base + 0) * 16 + h * 4 + 0];
  const float pv1 = pb4.y + ws[OFF_PC + (base + 1) * 16 + h * 4 + 1];
  const float pv2 = pb4.z + ws[OFF_PC + (base + 2) * 16 + h * 4 + 2];
  const float pv3 = pb4.w + ws[OFF_PC + (base + 3) * 16 + h * 4 + 3];
  const float w0 = ebc4.x * pv0, w1 = ebc4.y * pv1,
              w2 = ebc4.z * pv2, w3 = ebc4.w * pv3;

  #pragma unroll
  for (int rep = 0; rep < 2; ++rep) {
    const int aa = a + rep * 32;
    const int ah = (aa << 2) | h;
    const float eabz = ws[OFF_EAB + ah * N_B + bb] * ws[OFF_ZI + ah];
    const float4 eac4 = *(const float4*)(ws + OFF_EAC + ah * N_C + base);
    float acc = eac4.x * w0;
    acc = fmaf(eac4.y, w1, acc);
    acc = fmaf(eac4.z, w2, acc);
    acc = fmaf(eac4.w, w3, acc);
    const float x = fmaf(acc, eabz, fb);
    out[idx + rep * 524288] = 1.0f / (1.0f + __expf(-x));
  }
}

extern "C" void kernel_launch(void* const* d_in, const int* in_sizes, int n_in,
                              void* d_out, int out_size, void* d_ws, size_t ws_size,
                              hipStream_t stream) {
  const float* Ha  = (const float*)d_in[0];
  const float* Hb  = (const float*)d_in[1];
  const float* Hc  = (const float*)d_in[2];
  const float* Wq  = (const float*)d_in[3];
  const float* Wk  = (const float*)d_in[4];
  const float* Wv  = (const float*)d_in[5];
  const float* fcw = (const float*)d_in[6];
  const float* fcb = (const float*)d_in[7];
  float* out = (float*)d_out;
  float* ws  = (float*)d_ws;

  proj_kernel<<<288, 256, 0, stream>>>(Ha, Hb, Hc, Wq, Wk, Wv, ws);
  scores_kernel<<<528, 256, 0, stream>>>(fcw, ws);
  z_kernel<<<256, 256, 0, stream>>>(ws);
  out_kernel<<<2048, 256, 0, stream>>>(ws, fcb, out);
}